// Round 9
// baseline (558.590 us; speedup 1.0000x reference)
//
#include <hip/hip_runtime.h>
#include <hip/hip_bf16.h>

#define N_NODES 50000
#define N_EDGES 800000
#define F 64
#define N_GRAPHS 500
#define NW ((N_NODES + 63) / 64)   // 782 node-tiles of 64
#define PAD 65                     // LDS row pad: bank (lane+k)%32 -> 2-way (free)

// ---------------- CSR build step 1: deg[dst]++ ----------------
__global__ __launch_bounds__(256) void hist_kernel(
    const int* __restrict__ edge, int* __restrict__ deg)
{
    int e = blockIdx.x * 256 + threadIdx.x;
    if (e < N_EDGES) atomicAdd(&deg[edge[N_EDGES + e]], 1);
}

// ---------------- CSR build step 2a: per-64-chunk sums ----------------
__global__ __launch_bounds__(256) void wavesum_kernel(
    const int* __restrict__ deg, int* __restrict__ partial)
{
    int w = (blockIdx.x * 256 + threadIdx.x) >> 6;
    int lane = threadIdx.x & 63;
    if (w >= NW) return;
    int i = w * 64 + lane;
    int v = (i < N_NODES) ? deg[i] : 0;
#pragma unroll
    for (int d = 32; d > 0; d >>= 1) v += __shfl_xor(v, d);
    if (lane == 0) partial[w] = v;
}

// ---------------- CSR build step 2b: single-block exclusive scan of partial[NW] ----------------
__global__ __launch_bounds__(1024) void scanp_kernel(int* __restrict__ partial)
{
    __shared__ int ws[16];
    int t = threadIdx.x, lane = t & 63, wv = t >> 6;
    int v = (t < NW) ? partial[t] : 0;
    int incl = v;
#pragma unroll
    for (int d = 1; d < 64; d <<= 1) { int u = __shfl_up(incl, d); if (lane >= d) incl += u; }
    if (lane == 63) ws[wv] = incl;
    __syncthreads();
    if (wv == 0 && lane < 16) {
        int s = ws[lane];
#pragma unroll
        for (int d = 1; d < 16; d <<= 1) { int u = __shfl_up(s, d); if (lane >= d) s += u; }
        ws[lane] = s;
    }
    __syncthreads();
    int base = wv ? ws[wv - 1] : 0;
    if (t < NW) partial[t] = base + incl - v;     // exclusive scan in place
    if (t == 0) partial[NW] = ws[15];             // grand total
}

// ---------------- CSR build step 2c: per-chunk offsets ----------------
__global__ __launch_bounds__(256) void offsets_kernel(
    const int* __restrict__ deg, const int* __restrict__ partial,
    int* __restrict__ off, int* __restrict__ cursor)
{
    int w = (blockIdx.x * 256 + threadIdx.x) >> 6;
    int lane = threadIdx.x & 63;
    if (w >= NW) return;
    int i = w * 64 + lane;
    int v = (i < N_NODES) ? deg[i] : 0;
    int incl = v;
#pragma unroll
    for (int d = 1; d < 64; d <<= 1) { int u = __shfl_up(incl, d); if (lane >= d) incl += u; }
    int excl = partial[w] + incl - v;
    if (i < N_NODES) { off[i] = excl; cursor[i] = excl; }
    if (w == 0 && lane == 0) off[N_NODES] = partial[NW];
}

// ---------------- CSR build step 3: fill src lists ----------------
__global__ __launch_bounds__(256) void fill_kernel(
    const int* __restrict__ edge, int* __restrict__ cursor, int* __restrict__ csr_src)
{
    int e = blockIdx.x * 256 + threadIdx.x;
    if (e < N_EDGES) {
        int dst = edge[N_EDGES + e];
        int slot = atomicAdd(&cursor[dst], 1);
        csr_src[slot] = edge[e];
    }
}

// ---------------- gather: agg[n] = sum_{src in csr[n]} x[src]  (wave-per-node) ----------------
// csr indices wave-uniform -> s_load; row loads coalesced 256B; 8-deep MLP; no LDS, no barrier.
__global__ __launch_bounds__(256) void gather_kernel(
    const float* __restrict__ xin, const int* __restrict__ off,
    const int* __restrict__ csr_src, float* __restrict__ agg)
{
    int w = (blockIdx.x * 256 + threadIdx.x) >> 6;
    int lane = threadIdx.x & 63;
    if (w >= N_NODES) return;
    int beg = off[w], end = off[w + 1];
    float a0 = 0.f, a1 = 0.f, a2 = 0.f, a3 = 0.f;
    float a4 = 0.f, a5 = 0.f, a6 = 0.f, a7 = 0.f;
    int j = beg;
    for (; j + 8 <= end; j += 8) {
        int s0 = csr_src[j],     s1 = csr_src[j + 1], s2 = csr_src[j + 2], s3 = csr_src[j + 3];
        int s4 = csr_src[j + 4], s5 = csr_src[j + 5], s6 = csr_src[j + 6], s7 = csr_src[j + 7];
        a0 += xin[s0 * F + lane];
        a1 += xin[s1 * F + lane];
        a2 += xin[s2 * F + lane];
        a3 += xin[s3 * F + lane];
        a4 += xin[s4 * F + lane];
        a5 += xin[s5 * F + lane];
        a6 += xin[s6 * F + lane];
        a7 += xin[s7 * F + lane];
    }
    for (; j + 4 <= end; j += 4) {
        int s0 = csr_src[j], s1 = csr_src[j + 1], s2 = csr_src[j + 2], s3 = csr_src[j + 3];
        a0 += xin[s0 * F + lane];
        a1 += xin[s1 * F + lane];
        a2 += xin[s2 * F + lane];
        a3 += xin[s3 * F + lane];
    }
    for (; j < end; ++j) a0 += xin[csr_src[j] * F + lane];
    agg[w * F + lane] = ((a0 + a1) + (a2 + a3)) + ((a4 + a5) + (a6 + a7));
}

// ---------------- tiled GEMM: out = [relu](agg@Wrel^T + brel + x@Wroot^T) ----------------
// Block = 64-node tile, 4 waves. Stage A-tiles into LDS via coalesced float4 loads,
// then lane=node computes 16 outputs from LDS (pad-65, 2-way = free) with W via s_load.
__global__ __launch_bounds__(256) void gemm_kernel(
    const float* __restrict__ agg, const float* __restrict__ xin,
    const float* __restrict__ Wrel, const float* __restrict__ brel,
    const float* __restrict__ Wroot, float* __restrict__ out, int do_relu)
{
    __shared__ float sA[64 * PAD];   // agg tile
    __shared__ float sX[64 * PAD];   // x tile

    int tid = threadIdx.x;
    int n0 = blockIdx.x * 64;

    // ---- stage: 64 rows x 16 float4 per buffer, fully coalesced ----
    for (int i = tid; i < 64 * 16; i += 256) {
        int row = i >> 4, c4 = (i & 15) << 2;
        int node = n0 + row;
        float4 va, vx;
        if (node < N_NODES) {
            va = *reinterpret_cast<const float4*>(agg + (size_t)node * F + c4);
            vx = *reinterpret_cast<const float4*>(xin + (size_t)node * F + c4);
        } else {
            va = make_float4(0.f, 0.f, 0.f, 0.f);
            vx = make_float4(0.f, 0.f, 0.f, 0.f);
        }
        float* pa = sA + row * PAD + c4;
        float* px = sX + row * PAD + c4;
        pa[0] = va.x; pa[1] = va.y; pa[2] = va.z; pa[3] = va.w;
        px[0] = vx.x; px[1] = vx.y; px[2] = vx.z; px[3] = vx.w;
    }
    __syncthreads();

    // ---- compute: lane = node-in-tile, wave owns 16 outputs ----
    int lane = tid & 63;
    int ob = __builtin_amdgcn_readfirstlane((tid >> 6) * 16);
    int n = n0 + lane;

    float acc[16];
#pragma unroll
    for (int j = 0; j < 16; ++j) acc[j] = brel[ob + j];   // uniform -> s_load

#pragma unroll
    for (int half = 0; half < 2; ++half) {
        const float* __restrict__ W = half ? Wroot : Wrel;
        const float* __restrict__ s = half ? sX : sA;
#pragma unroll
        for (int kc = 0; kc < F; kc += 4) {
            float ax = s[lane * PAD + kc + 0];
            float ay = s[lane * PAD + kc + 1];
            float az = s[lane * PAD + kc + 2];
            float aw = s[lane * PAD + kc + 3];
#pragma unroll
            for (int j = 0; j < 16; ++j) {
                float4 wv = *reinterpret_cast<const float4*>(W + (ob + j) * F + kc);  // s_load_dwordx4
                acc[j] += ax * wv.x + ay * wv.y + az * wv.z + aw * wv.w;
            }
        }
    }
    if (do_relu) {
#pragma unroll
        for (int j = 0; j < 16; ++j) acc[j] = fmaxf(acc[j], 0.f);
    }
    if (n < N_NODES) {
#pragma unroll
        for (int j = 0; j < 16; j += 4)
            *reinterpret_cast<float4*>(out + (size_t)n * F + ob + j) =
                make_float4(acc[j], acc[j + 1], acc[j + 2], acc[j + 3]);
    }
}

// ---------------- fused pool (mean over contiguous node range) + head ----------------
__global__ __launch_bounds__(256) void pool_head_kernel(
    const float* __restrict__ h,
    const int* __restrict__ batch,   // sorted
    const float* __restrict__ Wlin,  // [2][64]
    const float* __restrict__ blin,  // [2]
    float* __restrict__ out)         // [N_GRAPHS][2]
{
    __shared__ float psum[4][F];
    __shared__ float pooled[F];
    int g = blockIdx.x;
    int tid = threadIdx.x, wave = tid >> 6, lane = tid & 63;

    int lo = 0, hi = N_NODES;
    while (lo < hi) { int mid = (lo + hi) >> 1; if (batch[mid] < g) lo = mid + 1; else hi = mid; }
    int s = lo;
    hi = N_NODES;
    while (lo < hi) { int mid = (lo + hi) >> 1; if (batch[mid] < g + 1) lo = mid + 1; else hi = mid; }
    int e = lo;

    float acc = 0.f;
    for (int n = s + wave; n < e; n += 4) acc += h[n * F + lane];
    psum[wave][lane] = acc;
    __syncthreads();
    if (wave == 0) {
        float p = psum[0][lane] + psum[1][lane] + psum[2][lane] + psum[3][lane];
        float c = (float)(e - s);
        pooled[lane] = p / fmaxf(c, 1.0f);
    }
    __syncthreads();
    if (tid < 2) {
        float acc2 = 0.f;
#pragma unroll
        for (int k = 0; k < F; ++k) acc2 += pooled[k] * Wlin[tid * F + k];
        out[g * 2 + tid] = acc2 + blin[tid];
    }
}

extern "C" void kernel_launch(void* const* d_in, const int* in_sizes, int n_in,
                              void* d_out, int out_size, void* d_ws, size_t ws_size,
                              hipStream_t stream) {
    const float* x     = (const float*)d_in[0];
    const int*   edge  = (const int*)d_in[1];
    const int*   batch = (const int*)d_in[2];
    const float* Wrel1 = (const float*)d_in[3];
    const float* brel1 = (const float*)d_in[4];
    const float* Wroot1= (const float*)d_in[5];
    const float* Wrel2 = (const float*)d_in[6];
    const float* brel2 = (const float*)d_in[7];
    const float* Wroot2= (const float*)d_in[8];
    const float* Wrel3 = (const float*)d_in[9];
    const float* brel3 = (const float*)d_in[10];
    const float* Wroot3= (const float*)d_in[11];
    const float* Wlin  = (const float*)d_in[12];
    const float* blin  = (const float*)d_in[13];
    float* out = (float*)d_out;

    char* ws = (char*)d_ws;
    size_t p = 0;
    int* deg     = (int*)(ws + p); p += (size_t)N_NODES * 4;
    int* off     = (int*)(ws + p); p += (size_t)(N_NODES + 1) * 4;
    int* cursor  = (int*)(ws + p); p += (size_t)N_NODES * 4;
    int* partial = (int*)(ws + p); p += (size_t)(NW + 1) * 4;
    p = (p + 255) & ~(size_t)255;
    int* csr_src = (int*)(ws + p); p += (size_t)N_EDGES * 4;
    p = (p + 255) & ~(size_t)255;
    float* agg   = (float*)(ws + p); p += (size_t)N_NODES * F * 4;
    float* hA    = (float*)(ws + p); p += (size_t)N_NODES * F * 4;
    float* hB    = (float*)(ws + p); p += (size_t)N_NODES * F * 4;

    dim3 blk(256);
    const int edgeBlocks = (N_EDGES + 255) / 256;   // 3125
    const int nodeWaveBlocks = (N_NODES + 3) / 4;   // 12500 (wave-per-node)
    const int segBlocks = (NW + 3) / 4;             // 196

    // ---- CSR build ----
    hipMemsetAsync(deg, 0, (size_t)N_NODES * 4, stream);
    hist_kernel<<<edgeBlocks, blk, 0, stream>>>(edge, deg);
    wavesum_kernel<<<segBlocks, blk, 0, stream>>>(deg, partial);
    scanp_kernel<<<1, 1024, 0, stream>>>(partial);
    offsets_kernel<<<segBlocks, blk, 0, stream>>>(deg, partial, off, cursor);
    fill_kernel<<<edgeBlocks, blk, 0, stream>>>(edge, cursor, csr_src);

    // ---- 3 GraphConv layers: gather (latency-optimized) + tiled GEMM (LDS-staged) ----
    gather_kernel<<<nodeWaveBlocks, blk, 0, stream>>>(x, off, csr_src, agg);
    gemm_kernel<<<NW, blk, 0, stream>>>(agg, x, Wrel1, brel1, Wroot1, hA, 1);

    gather_kernel<<<nodeWaveBlocks, blk, 0, stream>>>(hA, off, csr_src, agg);
    gemm_kernel<<<NW, blk, 0, stream>>>(agg, hA, Wrel2, brel2, Wroot2, hB, 1);

    gather_kernel<<<nodeWaveBlocks, blk, 0, stream>>>(hB, off, csr_src, agg);
    gemm_kernel<<<NW, blk, 0, stream>>>(agg, hB, Wrel3, brel3, Wroot3, hA, 0);

    // ---- fused mean-pool + head ----
    pool_head_kernel<<<N_GRAPHS, blk, 0, stream>>>(hA, batch, Wlin, blin, out);
}

// Round 10
// 393.515 us; speedup vs baseline: 1.4195x; 1.4195x over previous
//
#include <hip/hip_runtime.h>
#include <hip/hip_bf16.h>

#define N_NODES 50000
#define N_EDGES 800000
#define F 64
#define N_GRAPHS 500
#define NW ((N_NODES + 63) / 64)   // 782 node-tiles of 64
#define PADW 68                    // A-tile pad (float4-aligned): bank-grp (lane+kc/4)%8 -> even

// ---------------- CSR build step 1: deg[dst]++ ----------------
__global__ __launch_bounds__(256) void hist_kernel(
    const int* __restrict__ edge, int* __restrict__ deg)
{
    int e = blockIdx.x * 256 + threadIdx.x;
    if (e < N_EDGES) atomicAdd(&deg[edge[N_EDGES + e]], 1);
}

// ---------------- CSR build step 2a: per-64-chunk sums ----------------
__global__ __launch_bounds__(256) void wavesum_kernel(
    const int* __restrict__ deg, int* __restrict__ partial)
{
    int w = (blockIdx.x * 256 + threadIdx.x) >> 6;
    int lane = threadIdx.x & 63;
    if (w >= NW) return;
    int i = w * 64 + lane;
    int v = (i < N_NODES) ? deg[i] : 0;
#pragma unroll
    for (int d = 32; d > 0; d >>= 1) v += __shfl_xor(v, d);
    if (lane == 0) partial[w] = v;
}

// ---------------- CSR build step 2b: single-block exclusive scan of partial[NW] ----------------
__global__ __launch_bounds__(1024) void scanp_kernel(int* __restrict__ partial)
{
    __shared__ int ws[16];
    int t = threadIdx.x, lane = t & 63, wv = t >> 6;
    int v = (t < NW) ? partial[t] : 0;
    int incl = v;
#pragma unroll
    for (int d = 1; d < 64; d <<= 1) { int u = __shfl_up(incl, d); if (lane >= d) incl += u; }
    if (lane == 63) ws[wv] = incl;
    __syncthreads();
    if (wv == 0 && lane < 16) {
        int s = ws[lane];
#pragma unroll
        for (int d = 1; d < 16; d <<= 1) { int u = __shfl_up(s, d); if (lane >= d) s += u; }
        ws[lane] = s;
    }
    __syncthreads();
    int base = wv ? ws[wv - 1] : 0;
    if (t < NW) partial[t] = base + incl - v;     // exclusive scan in place
    if (t == 0) partial[NW] = ws[15];             // grand total
}

// ---------------- CSR build step 2c: per-chunk offsets ----------------
__global__ __launch_bounds__(256) void offsets_kernel(
    const int* __restrict__ deg, const int* __restrict__ partial,
    int* __restrict__ off, int* __restrict__ cursor)
{
    int w = (blockIdx.x * 256 + threadIdx.x) >> 6;
    int lane = threadIdx.x & 63;
    if (w >= NW) return;
    int i = w * 64 + lane;
    int v = (i < N_NODES) ? deg[i] : 0;
    int incl = v;
#pragma unroll
    for (int d = 1; d < 64; d <<= 1) { int u = __shfl_up(incl, d); if (lane >= d) incl += u; }
    int excl = partial[w] + incl - v;
    if (i < N_NODES) { off[i] = excl; cursor[i] = excl; }
    if (w == 0 && lane == 0) off[N_NODES] = partial[NW];
}

// ---------------- CSR build step 3: fill src lists ----------------
__global__ __launch_bounds__(256) void fill_kernel(
    const int* __restrict__ edge, int* __restrict__ cursor, int* __restrict__ csr_src)
{
    int e = blockIdx.x * 256 + threadIdx.x;
    if (e < N_EDGES) {
        int dst = edge[N_EDGES + e];
        int slot = atomicAdd(&cursor[dst], 1);
        csr_src[slot] = edge[e];
    }
}

// ---------------- gather v2: wave-per-node, float4 lanes, 4 edges per pass ----------------
// 16 lanes x float4 cover one 256B row; lane-groups g=0..3 take edge slots base+g+4k;
// 16 row-loads in flight per wave; __shfl_xor reduce across groups; b128 store.
__global__ __launch_bounds__(256) void gather_kernel(
    const float* __restrict__ xin, const int* __restrict__ off,
    const int* __restrict__ csr_src, float* __restrict__ agg)
{
    int w = (blockIdx.x * 256 + threadIdx.x) >> 6;   // node
    int lane = threadIdx.x & 63;
    if (w >= N_NODES) return;
    int g = lane >> 4;            // edge slot group 0..3
    int q = (lane & 15) << 2;     // feature quad offset 0..60

    int beg = off[w], end = off[w + 1];
    float4 a0 = make_float4(0.f, 0.f, 0.f, 0.f);
    float4 a1 = a0, a2 = a0, a3 = a0;

    for (int base = beg; base < end; base += 16) {
        int e0 = base + g, e1 = e0 + 4, e2 = e0 + 8, e3 = e0 + 12;
        if (e0 < end) {
            const float4 v = *reinterpret_cast<const float4*>(xin + (size_t)csr_src[e0] * F + q);
            a0.x += v.x; a0.y += v.y; a0.z += v.z; a0.w += v.w;
        }
        if (e1 < end) {
            const float4 v = *reinterpret_cast<const float4*>(xin + (size_t)csr_src[e1] * F + q);
            a1.x += v.x; a1.y += v.y; a1.z += v.z; a1.w += v.w;
        }
        if (e2 < end) {
            const float4 v = *reinterpret_cast<const float4*>(xin + (size_t)csr_src[e2] * F + q);
            a2.x += v.x; a2.y += v.y; a2.z += v.z; a2.w += v.w;
        }
        if (e3 < end) {
            const float4 v = *reinterpret_cast<const float4*>(xin + (size_t)csr_src[e3] * F + q);
            a3.x += v.x; a3.y += v.y; a3.z += v.z; a3.w += v.w;
        }
    }
    float4 acc;
    acc.x = (a0.x + a1.x) + (a2.x + a3.x);
    acc.y = (a0.y + a1.y) + (a2.y + a3.y);
    acc.z = (a0.z + a1.z) + (a2.z + a3.z);
    acc.w = (a0.w + a1.w) + (a2.w + a3.w);
    // reduce across the 4 groups (lanes differing in bits 4,5)
#pragma unroll
    for (int d = 16; d <= 32; d <<= 1) {
        acc.x += __shfl_xor(acc.x, d);
        acc.y += __shfl_xor(acc.y, d);
        acc.z += __shfl_xor(acc.z, d);
        acc.w += __shfl_xor(acc.w, d);
    }
    if (lane < 16)
        *reinterpret_cast<float4*>(agg + (size_t)w * F + q) = acc;
}

// ---------------- gemm v2: both operands from LDS ----------------
// Block = 64-node tile, 4 waves. A/X tiles padded (conflict-free per-lane b128);
// Wrel/Wroot staged flat -- uniform-address ds_read_b128 broadcasts (free).
// lane = node, wave owns 16 outputs.
__global__ __launch_bounds__(256) void gemm_kernel(
    const float* __restrict__ agg, const float* __restrict__ xin,
    const float* __restrict__ Wrel, const float* __restrict__ brel,
    const float* __restrict__ Wroot, float* __restrict__ out, int do_relu)
{
    __shared__ float sA[64 * PADW];
    __shared__ float sX[64 * PADW];
    __shared__ float sWrel[64 * 64];
    __shared__ float sWroot[64 * 64];

    int tid = threadIdx.x;
    int n0 = blockIdx.x * 64;

    // ---- stage A and X tiles (coalesced float4) ----
    for (int i = tid; i < 64 * 16; i += 256) {
        int row = i >> 4, c4 = (i & 15) << 2;
        int node = n0 + row;
        float4 va = make_float4(0.f, 0.f, 0.f, 0.f), vx = va;
        if (node < N_NODES) {
            va = *reinterpret_cast<const float4*>(agg + (size_t)node * F + c4);
            vx = *reinterpret_cast<const float4*>(xin + (size_t)node * F + c4);
        }
        *reinterpret_cast<float4*>(sA + row * PADW + c4) = va;
        *reinterpret_cast<float4*>(sX + row * PADW + c4) = vx;
    }
    // ---- stage W matrices (flat 16 KB each) ----
    for (int i = tid; i < 64 * 16; i += 256) {
        int idx = i << 2;
        *reinterpret_cast<float4*>(sWrel + idx)  = *reinterpret_cast<const float4*>(Wrel + idx);
        *reinterpret_cast<float4*>(sWroot + idx) = *reinterpret_cast<const float4*>(Wroot + idx);
    }
    __syncthreads();

    // ---- compute: lane = node-in-tile, wave owns 16 outputs ----
    int lane = tid & 63;
    int ob = __builtin_amdgcn_readfirstlane((tid >> 6) * 16);
    int n = n0 + lane;

    float acc[16];
#pragma unroll
    for (int j = 0; j < 16; ++j) acc[j] = brel[ob + j];   // uniform -> s_load

#pragma unroll
    for (int half = 0; half < 2; ++half) {
        const float* __restrict__ sW = half ? sWroot : sWrel;
        const float* __restrict__ s  = half ? sX : sA;
#pragma unroll
        for (int kc = 0; kc < F; kc += 4) {
            float4 a = *reinterpret_cast<const float4*>(s + lane * PADW + kc);
#pragma unroll
            for (int j = 0; j < 16; ++j) {
                // uniform LDS address -> broadcast ds_read_b128 (no bank conflict)
                float4 wv = *reinterpret_cast<const float4*>(sW + (ob + j) * F + kc);
                acc[j] += a.x * wv.x + a.y * wv.y + a.z * wv.z + a.w * wv.w;
            }
        }
    }
    if (do_relu) {
#pragma unroll
        for (int j = 0; j < 16; ++j) acc[j] = fmaxf(acc[j], 0.f);
    }
    if (n < N_NODES) {
#pragma unroll
        for (int j = 0; j < 16; j += 4)
            *reinterpret_cast<float4*>(out + (size_t)n * F + ob + j) =
                make_float4(acc[j], acc[j + 1], acc[j + 2], acc[j + 3]);
    }
}

// ---------------- fused pool (mean over contiguous node range) + head ----------------
__global__ __launch_bounds__(256) void pool_head_kernel(
    const float* __restrict__ h,
    const int* __restrict__ batch,   // sorted
    const float* __restrict__ Wlin,  // [2][64]
    const float* __restrict__ blin,  // [2]
    float* __restrict__ out)         // [N_GRAPHS][2]
{
    __shared__ float psum[4][F];
    __shared__ float pooled[F];
    int g = blockIdx.x;
    int tid = threadIdx.x, wave = tid >> 6, lane = tid & 63;

    int lo = 0, hi = N_NODES;
    while (lo < hi) { int mid = (lo + hi) >> 1; if (batch[mid] < g) lo = mid + 1; else hi = mid; }
    int s = lo;
    hi = N_NODES;
    while (lo < hi) { int mid = (lo + hi) >> 1; if (batch[mid] < g + 1) lo = mid + 1; else hi = mid; }
    int e = lo;

    float acc = 0.f;
    for (int n = s + wave; n < e; n += 4) acc += h[n * F + lane];
    psum[wave][lane] = acc;
    __syncthreads();
    if (wave == 0) {
        float p = psum[0][lane] + psum[1][lane] + psum[2][lane] + psum[3][lane];
        float c = (float)(e - s);
        pooled[lane] = p / fmaxf(c, 1.0f);
    }
    __syncthreads();
    if (tid < 2) {
        float acc2 = 0.f;
#pragma unroll
        for (int k = 0; k < F; ++k) acc2 += pooled[k] * Wlin[tid * F + k];
        out[g * 2 + tid] = acc2 + blin[tid];
    }
}

extern "C" void kernel_launch(void* const* d_in, const int* in_sizes, int n_in,
                              void* d_out, int out_size, void* d_ws, size_t ws_size,
                              hipStream_t stream) {
    const float* x     = (const float*)d_in[0];
    const int*   edge  = (const int*)d_in[1];
    const int*   batch = (const int*)d_in[2];
    const float* Wrel1 = (const float*)d_in[3];
    const float* brel1 = (const float*)d_in[4];
    const float* Wroot1= (const float*)d_in[5];
    const float* Wrel2 = (const float*)d_in[6];
    const float* brel2 = (const float*)d_in[7];
    const float* Wroot2= (const float*)d_in[8];
    const float* Wrel3 = (const float*)d_in[9];
    const float* brel3 = (const float*)d_in[10];
    const float* Wroot3= (const float*)d_in[11];
    const float* Wlin  = (const float*)d_in[12];
    const float* blin  = (const float*)d_in[13];
    float* out = (float*)d_out;

    char* ws = (char*)d_ws;
    size_t p = 0;
    int* deg     = (int*)(ws + p); p += (size_t)N_NODES * 4;
    int* off     = (int*)(ws + p); p += (size_t)(N_NODES + 1) * 4;
    int* cursor  = (int*)(ws + p); p += (size_t)N_NODES * 4;
    int* partial = (int*)(ws + p); p += (size_t)(NW + 1) * 4;
    p = (p + 255) & ~(size_t)255;
    int* csr_src = (int*)(ws + p); p += (size_t)N_EDGES * 4;
    p = (p + 255) & ~(size_t)255;
    float* agg   = (float*)(ws + p); p += (size_t)N_NODES * F * 4;
    float* hA    = (float*)(ws + p); p += (size_t)N_NODES * F * 4;
    float* hB    = (float*)(ws + p); p += (size_t)N_NODES * F * 4;

    dim3 blk(256);
    const int edgeBlocks = (N_EDGES + 255) / 256;   // 3125
    const int nodeWaveBlocks = (N_NODES + 3) / 4;   // 12500 (wave-per-node)
    const int segBlocks = (NW + 3) / 4;             // 196

    // ---- CSR build ----
    hipMemsetAsync(deg, 0, (size_t)N_NODES * 4, stream);
    hist_kernel<<<edgeBlocks, blk, 0, stream>>>(edge, deg);
    wavesum_kernel<<<segBlocks, blk, 0, stream>>>(deg, partial);
    scanp_kernel<<<1, 1024, 0, stream>>>(partial);
    offsets_kernel<<<segBlocks, blk, 0, stream>>>(deg, partial, off, cursor);
    fill_kernel<<<edgeBlocks, blk, 0, stream>>>(edge, cursor, csr_src);

    // ---- 3 GraphConv layers: gather (float4/MLP) + GEMM (all-LDS operands) ----
    gather_kernel<<<nodeWaveBlocks, blk, 0, stream>>>(x, off, csr_src, agg);
    gemm_kernel<<<NW, blk, 0, stream>>>(agg, x, Wrel1, brel1, Wroot1, hA, 1);

    gather_kernel<<<nodeWaveBlocks, blk, 0, stream>>>(hA, off, csr_src, agg);
    gemm_kernel<<<NW, blk, 0, stream>>>(agg, hA, Wrel2, brel2, Wroot2, hB, 1);

    gather_kernel<<<nodeWaveBlocks, blk, 0, stream>>>(hB, off, csr_src, agg);
    gemm_kernel<<<NW, blk, 0, stream>>>(agg, hB, Wrel3, brel3, Wroot3, hA, 0);

    // ---- fused mean-pool + head ----
    pool_head_kernel<<<N_GRAPHS, blk, 0, stream>>>(hA, batch, Wlin, blin, out);
}